// Round 11
// baseline (122.396 us; speedup 1.0000x reference)
//
#include <hip/hip_runtime.h>

#define N_NODES 100000
#define N_EDGES 3200000
#define NVEC    (N_EDGES / 4)           // 800000 int4 per stream

#define S_LOG2  8
#define S       (1 << S_LOG2)           // 256 nodes per partition
#define NPART   ((N_NODES + S - 1) / S) // 391 partitions
#define NPB     448                     // NPART padded to x64 for the scan
#define TROW    NPART                   // tab row: 391 packed (off<<16|cnt)

#define EPB     6144                    // edges per chunk: nv = 1536 = 3*512
#define NCH     ((N_EDGES + EPB - 1) / EPB)  // 521 chunks
#define LMAX    8896                    // max padded chunk (6144+391*7 -> 16-align)
#define CSTR    LMAX                    // buckets2 chunk stride (64B aligned)
#define CAP     9216                    // S2 capacity (mean 8184, +11 sigma)
#define PIT     9                       // part iterations: ceil(521/64)

constexpr float DSIGMA_DT  = -0.0001f;
constexpr float PHI_THRESH = 0.3f;
constexpr float EPS        = 1e-8f;

// ---------------- Pass A: chunk-local counting sort, LINEAR padded write ---
// R10 proved linear write-out puts bin at its model floor (~23 us). CHANGE:
// segments are padded to 8-int (32B) boundaries inside the LDS sort, so
// part's 16-lane segment reads are 32B-ALIGNED (1.2 lines vs 2.0), and tab
// packs (paddedOff<<16)|cnt -> ONE tab load per (group,chunk) on the read
// side. Write grows 12.8->18.5MB but stays full-line linear (cheap side).
// 39 KB LDS -> 4 blocks/CU (32 waves, 100% occupancy).
__global__ __launch_bounds__(512, 8) void bin_kernel(
        const int4* __restrict__ ei4,
        const float* __restrict__ x,
        const float* __restrict__ pos,
        float4* __restrict__ posT,
        int* __restrict__ tab,
        int* __restrict__ buckets2) {
    __shared__ int lbuf[LMAX];             // 35.6 KB padded partition-sorted
    __shared__ int hist[NPB], lofs[NPB];   // 3.5 KB (raw counts / padded offs)
    __shared__ int ntot;
    const int tid = threadIdx.x;
    const int c   = blockIdx.x;

    // fused prep: slice of posT
    {
        const int per = (N_NODES + NCH - 1) / NCH;   // 192
        const int lo = c * per;
        const int hi = min(lo + per, N_NODES);
        for (int i = lo + tid; i < hi; i += 512)
            posT[i] = make_float4(pos[3 * i], pos[3 * i + 1], pos[3 * i + 2],
                                  x[9 * i + 3]);
    }

    const int ebase = c * EPB;
    const int n  = min(EPB, N_EDGES - ebase);   // multiple of 4
    const int nv = n >> 2;
    const int4* __restrict__ src4 = ei4 + (ebase >> 2);
    const int4* __restrict__ dst4 = ei4 + NVEC + (ebase >> 2);

    for (int i = tid; i < NPB; i += 512) hist[i] = 0;
    __syncthreads();

    // single global read of edges into REGISTERS; histogram with rank
    // capture into REGISTERS (1 returning LDS atomic per edge)
    int4 rs[3], rd[3];
    unsigned short rk[12];
#pragma unroll
    for (int k = 0; k < 3; ++k) {
        int v = tid + k * 512;
        if (v < nv) {
            rs[k] = src4[v];
            rd[k] = dst4[v];
            rk[4 * k + 0] = (unsigned short)atomicAdd(&hist[rd[k].x >> S_LOG2], 1);
            rk[4 * k + 1] = (unsigned short)atomicAdd(&hist[rd[k].y >> S_LOG2], 1);
            rk[4 * k + 2] = (unsigned short)atomicAdd(&hist[rd[k].z >> S_LOG2], 1);
            rk[4 * k + 3] = (unsigned short)atomicAdd(&hist[rd[k].w >> S_LOG2], 1);
        }
    }
    __syncthreads();

    // wave-0 exclusive prefix over PADDED counts (7 x 64 with carry):
    // each segment rounded up to 8 ints -> 32B-aligned starts.
    if (tid < 64) {
        int carry = 0;
        for (int b = 0; b < NPB; b += 64) {
            int v = (hist[b + tid] + 7) & ~7;
            int orig = v;
#pragma unroll
            for (int d = 1; d < 64; d <<= 1) {
                int t = __shfl_up(v, d, 64);
                if (tid >= d) v += t;
            }
            lofs[b + tid] = carry + v - orig;
            carry += __shfl(v, 63, 64);
        }
        if (tid == 0) ntot = carry;       // total padded length (<= 8881)
    }
    __syncthreads();

    // packed offset table: ONE int per (chunk, partition)
    for (int p = tid; p < NPART; p += 512)
        tab[c * TROW + p] = (lofs[p] << 16) | hist[p];

    // scatter from registers into padded partition-sorted LDS
#pragma unroll
    for (int k = 0; k < 3; ++k) {
        int v = tid + k * 512;
        if (v < nv) {
#pragma unroll
            for (int j = 0; j < 4; ++j) {
                int dk = j == 0 ? rd[k].x : j == 1 ? rd[k].y : j == 2 ? rd[k].z : rd[k].w;
                int sk = j == 0 ? rs[k].x : j == 1 ? rs[k].y : j == 2 ? rs[k].z : rs[k].w;
                int bin = dk >> S_LOG2;
                lbuf[lofs[bin] + (int)rk[4 * k + j]] =
                    (sk << S_LOG2) | (dk & (S - 1));
            }
        }
    }
    __syncthreads();

    // LINEAR chunk write-out (full 64B lines; pad slots carry garbage that
    // the read side masks via cnt)
    const int nt = ntot;
    for (int i = tid; i < nt; i += 512)
        buckets2[(size_t)c * CSTR + i] = lbuf[i];
}

// ---------------- Pass B: chunk-segment gather + node sort + fused final ---
// Partition p gathers its 521 segments: 16-lane groups, ONE packed tab load
// per chunk (off<<16|cnt), 32B-aligned segment reads. Entries+ranks live in
// REGISTERS across the 9 unrolled iterations (1 returning LDS atomic/edge),
// then scatter to node-sorted S2, 4-thread/node reduce, fused epilogue.
__global__ __launch_bounds__(1024, 4) void part_kernel(
        const int* __restrict__ tab,
        const int* __restrict__ buckets2,
        const float4* __restrict__ posT,
        const float* __restrict__ x,
        float* __restrict__ out) {
    __shared__ int S2[CAP];                // 36.9 KB node-sorted src ids
    __shared__ int hist[S], base[S];       // 2 KB
    __shared__ float4 ploc[S];             // 4 KB partition's posT slice
    const int p = blockIdx.x, tid = threadIdx.x;
    const int lo = p << S_LOG2;

    if (tid < S) {
        hist[tid] = 0;
        int node = lo + tid;
        ploc[tid] = (node < N_NODES) ? posT[node] : make_float4(0.f, 0.f, 0.f, 0.f);
    }
    __syncthreads();

    // phase 1: gather segments + rank capture, all state in registers.
    // group g = tid>>4 (64 groups), lane j = tid&15; chunk c = it*64+g.
    const int g = tid >> 4, j = tid & 15;
    int ent[PIT][4];
    unsigned short prk[PIT][4];
    int cnt[PIT];
#pragma unroll
    for (int it = 0; it < PIT; ++it) {
        const int c = it * 64 + g;
        cnt[it] = 0;
        if (c < NCH) {
            int u = tab[c * TROW + p];             // ONE packed load
            int o0 = u >> 16;
            cnt[it] = u & 0xFFFF;
            const int* seg = buckets2 + (size_t)c * CSTR + o0;  // 32B-aligned
#pragma unroll
            for (int r = 0; r < 4; ++r) {
                int idx = j + 16 * r;
                if (idx < cnt[it]) {
                    int e = seg[idx];
                    ent[it][r] = e;
                    prk[it][r] = (unsigned short)atomicAdd(&hist[e & (S - 1)], 1);
                }
            }
        }
    }
    __syncthreads();

    // exclusive prefix scan of hist[0..256) by wave 0 (4 x 64 with carry)
    if (tid < 64) {
        int carry = 0;
        for (int b = 0; b < S; b += 64) {
            int v = hist[b + tid];
            int orig = v;
#pragma unroll
            for (int d = 1; d < 64; d <<= 1) {
                int t = __shfl_up(v, d, 64);
                if (tid >= d) v += t;
            }
            base[b + tid] = carry + v - orig;
            carry += __shfl(v, 63, 64);
        }
    }
    __syncthreads();

    // phase 2: replay from registers, scatter into node-sorted S2
#pragma unroll
    for (int it = 0; it < PIT; ++it) {
#pragma unroll
        for (int r = 0; r < 4; ++r) {
            int idx = j + 16 * r;
            if (idx < cnt[it]) {
                int e = ent[it][r];
                int pos = base[e & (S - 1)] + (int)prk[it][r];
                if (pos < CAP) S2[pos] = e >> S_LOG2;
            }
        }
    }
    __syncthreads();

    // fused reduce + finalize: 4 threads per node, quad shuffle combine.
    // tid = r*4 + q ; rows r in [0,256), q in [0,4). 1024 = S*4 exactly.
    const int rr = tid >> 2, q = tid & 3;
    const int node = lo + rr;
    const int nseg = hist[rr];
    const int b0 = base[rr];
    const int jend = min(b0 + nseg, CAP);
    float4 b = ploc[rr];
    float ax = 0.f, ay = 0.f, az = 0.f;
    for (int jj = b0 + q; jj < jend; jj += 4) {
        float4 a = posT[S2[jj]];
        float px = a.x - b.x, py = a.y - b.y, pz = a.z - b.z;
        float dT = a.w - b.w;
        float w  = dT / (px * px + py * py + pz * pz + EPS);
        ax += w * px; ay += w * py; az += w * pz;
    }
    ax += __shfl_down(ax, 2, 64); ax += __shfl_down(ax, 1, 64);
    ay += __shfl_down(ay, 2, 64); ay += __shfl_down(ay, 1, 64);
    az += __shfl_down(az, 2, 64); az += __shfl_down(az, 1, 64);
    if (q == 0 && node < N_NODES) {
        float phi = x[node * 9 + 8];
        float cn = nseg > 1 ? (float)nseg : 1.0f;
        float m = (fabsf(phi) < PHI_THRESH) ? (DSIGMA_DT / cn) : 0.0f;
        out[3 * node]     = m * ax;
        out[3 * node + 1] = m * ay;
        out[3 * node + 2] = m * az;
    }
}

// ---------------- fallback: global atomics (small ws) ---------------------
__global__ void prep_kernel(const float* __restrict__ x,
                            const float* __restrict__ pos,
                            float4* __restrict__ posT) {
    int i = blockIdx.x * blockDim.x + threadIdx.x;
    if (i < N_NODES)
        posT[i] = make_float4(pos[3 * i], pos[3 * i + 1], pos[3 * i + 2],
                              x[9 * i + 3]);
}

__global__ void edge_scatter_atomic_kernel(const int* __restrict__ ei,
                                           const float4* __restrict__ posT,
                                           float4* __restrict__ accum) {
    int e = blockIdx.x * blockDim.x + threadIdx.x;
    if (e >= N_EDGES) return;
    int s = ei[e];
    int d = ei[N_EDGES + e];
    float4 a = posT[s];
    float4 b = posT[d];
    float px = a.x - b.x, py = a.y - b.y, pz = a.z - b.z;
    float dT = a.w - b.w;
    float w  = dT / (px * px + py * py + pz * pz + EPS);
    float* ac = (float*)&accum[d];
    atomicAdd(ac,     w * px);
    atomicAdd(ac + 1, w * py);
    atomicAdd(ac + 2, w * pz);
    atomicAdd(ac + 3, 1.0f);
}

__global__ void finalize_accum_kernel(const float* __restrict__ x,
                                      const float4* __restrict__ accum,
                                      float* __restrict__ out) {
    int i = blockIdx.x * blockDim.x + threadIdx.x;
    if (i >= N_NODES) return;
    float4 a = accum[i];
    float phi = x[i * 9 + 8];
    float cn = a.w > 1.0f ? a.w : 1.0f;
    float m = (fabsf(phi) < PHI_THRESH) ? (DSIGMA_DT / cn) : 0.0f;
    out[3 * i]     = m * a.x;
    out[3 * i + 1] = m * a.y;
    out[3 * i + 2] = m * a.z;
}

extern "C" void kernel_launch(void* const* d_in, const int* in_sizes, int n_in,
                              void* d_out, int out_size, void* d_ws, size_t ws_size,
                              hipStream_t stream) {
    const float* x   = (const float*)d_in[0];
    const float* pos = (const float*)d_in[1];
    const int*   ei  = (const int*)d_in[2];
    float* out = (float*)d_out;

    // ws layout: [posT 1.6MB][tab 815KB][buckets2 18.5MB] ~ 21MB
    const size_t posT_b = (size_t)N_NODES * sizeof(float4);             // 1.6 MB
    const size_t tab_b  = ((size_t)NCH * TROW * sizeof(int) + 255) & ~255ull;
    const size_t buck_b = (size_t)NCH * CSTR * sizeof(int);             // 18.5 MB

    char* w = (char*)d_ws;
    float4* posT     = (float4*)w;
    int*    tab      = (int*)(w + posT_b);
    int*    buckets2 = (int*)(w + posT_b + tab_b);

    const size_t need_full = posT_b + tab_b + buck_b;                   // ~21 MB

    const int B = 256;

    if (ws_size >= need_full) {
        bin_kernel<<<NCH, 512, 0, stream>>>((const int4*)ei, x, pos, posT, tab, buckets2);
        part_kernel<<<NPART, 1024, 0, stream>>>(tab, buckets2, posT, x, out);
    } else {
        float4* accum = (float4*)(w + posT_b);  // 1.6 MB
        prep_kernel<<<(N_NODES + B - 1) / B, B, 0, stream>>>(x, pos, posT);
        hipMemsetAsync(accum, 0, (size_t)N_NODES * sizeof(float4), stream);
        edge_scatter_atomic_kernel<<<(N_EDGES + B - 1) / B, B, 0, stream>>>(ei, posT, accum);
        finalize_accum_kernel<<<(N_NODES + B - 1) / B, B, 0, stream>>>(x, accum, out);
    }
}

// Round 12
// 113.294 us; speedup vs baseline: 1.0803x; 1.0803x over previous
//
#include <hip/hip_runtime.h>

#define N_NODES 100000
#define N_EDGES 3200000
#define NVEC    (N_EDGES / 4)           // 800000 int4 per stream

#define S_LOG2  8
#define S       (1 << S_LOG2)           // 256 nodes per partition
#define NPART   ((N_NODES + S - 1) / S) // 391 partitions
#define NPB     448                     // NPART padded to x64 for the scan
#define GSTRIDE 16                      // gcur padded to 64B/counter
#define NXCD    8                       // per-XCD bucket replicas
#define CAP8    1536                    // per-(xcd,partition) capacity (mean 1023, +16s)

#define BT      1024                    // block threads (16 waves)
#define EPB     6252                    // edges per bin block (mult of 4)
#define NB      ((N_EDGES + EPB - 1) / EPB)  // 512 blocks = 64 per XCD exactly
#define CAP     9216                    // S2 capacity (mean 8184, +11 sigma)

constexpr float DSIGMA_DT  = -0.0001f;
constexpr float PHI_THRESH = 0.3f;
constexpr float EPS        = 1e-8f;

// ---------------- Pass A: counting-sort into XCD-LOCAL partition buckets ---
// R4 showed the bucket scatter-write runs at ~1.2 TB/s effective due to 4.5x
// write amplification; R10/R11 showed moving the scatter to the read side
// costs the same ~20us. Root cause: adjacent runs of one bucket are written
// by blocks on DIFFERENT XCDs -> partial-line RMW in non-coherent L2s.
// FIX: 8 bucket replicas, indexed xcd = blockIdx.x & 7 (round-robin
// dispatch heuristic; correctness independent of mapping). Blocks of one
// XCD share one L2, which merges their partial lines -> full-line writebacks.
// Sort structure unchanged from R9 (proven): 1 returning LDS atomic/edge.
__global__ __launch_bounds__(BT, 8) void bin_kernel(const int4* __restrict__ ei4,
                                                    const float* __restrict__ x,
                                                    const float* __restrict__ pos,
                                                    float4* __restrict__ posT,
                                                    int* __restrict__ gcur,
                                                    int* __restrict__ buckets) {
    __shared__ int   lbuf[EPB];            // 25 KB sorted entries (sk<<8 | dk&255)
    __shared__ unsigned short lrk[EPB];    // 12.5 KB per-entry rank
    __shared__ unsigned short lbinS[EPB];  // 12.5 KB bin id of sorted entry
    __shared__ int hist[NPB], lofs[NPB];   // 3.5 KB
    __shared__ int baseg[NPART];           // 1.6 KB
    const int tid = threadIdx.x;
    const int xcd = blockIdx.x & (NXCD - 1);

    // fused prep: slice of posT
    {
        const int per = (N_NODES + NB - 1) / NB;   // 196
        const int lo = blockIdx.x * per;
        const int hi = min(lo + per, N_NODES);
        for (int i = lo + tid; i < hi; i += BT)
            posT[i] = make_float4(pos[3 * i], pos[3 * i + 1], pos[3 * i + 2],
                                  x[9 * i + 3]);
    }

    const int ebase = blockIdx.x * EPB;
    const int n  = min(EPB, N_EDGES - ebase);   // multiple of 4
    const int nv = n >> 2;
    const int4* __restrict__ src4 = ei4 + (ebase >> 2);
    const int4* __restrict__ dst4 = ei4 + NVEC + (ebase >> 2);

    for (int i = tid; i < NPB; i += BT) hist[i] = 0;
    __syncthreads();

    // loop 1: histogram with rank capture (1 returning LDS atomic per edge)
    for (int v = tid; v < nv; v += BT) {
        int4 d = dst4[v];
        ushort4 rk;
        rk.x = (unsigned short)atomicAdd(&hist[d.x >> S_LOG2], 1);
        rk.y = (unsigned short)atomicAdd(&hist[d.y >> S_LOG2], 1);
        rk.z = (unsigned short)atomicAdd(&hist[d.z >> S_LOG2], 1);
        rk.w = (unsigned short)atomicAdd(&hist[d.w >> S_LOG2], 1);
        ((ushort4*)lrk)[v] = rk;
    }
    __syncthreads();

    // wave-0 exclusive prefix over 448 padded bins (7 x 64 with carry)
    if (tid < 64) {
        int carry = 0;
        for (int b = 0; b < NPB; b += 64) {
            int v = hist[b + tid];
            int orig = v;
#pragma unroll
            for (int d = 1; d < 64; d <<= 1) {
                int t = __shfl_up(v, d, 64);
                if (tid >= d) v += t;
            }
            lofs[b + tid] = carry + v - orig;
            carry += __shfl(v, 63, 64);
        }
    }
    __syncthreads();
    // allocation in the XCD-local counter block
    if (tid < NPART)
        baseg[tid] = atomicAdd(&gcur[(xcd * NPART + tid) * GSTRIDE], hist[tid]);
    __syncthreads();

    // loop 2: re-read edge slice (L2-hot), place entries with plain writes
    for (int v = tid; v < nv; v += BT) {
        int4 s = src4[v];
        int4 d = dst4[v];
        ushort4 rk = ((const ushort4*)lrk)[v];
#pragma unroll
        for (int k = 0; k < 4; ++k) {
            int dk = k == 0 ? d.x : k == 1 ? d.y : k == 2 ? d.z : d.w;
            int sk = k == 0 ? s.x : k == 1 ? s.y : k == 2 ? s.z : s.w;
            int rr = k == 0 ? rk.x : k == 1 ? rk.y : k == 2 ? rk.z : rk.w;
            int bin = dk >> S_LOG2;
            int pos = lofs[bin] + rr;
            lbuf[pos]  = (sk << S_LOG2) | (dk & (S - 1));
            lbinS[pos] = (unsigned short)bin;
        }
    }
    __syncthreads();

    // dense copy-out into the XCD-LOCAL bucket replica
    for (int i = tid; i < n; i += BT) {
        int b   = lbinS[i];
        int pos = baseg[b] + (i - lofs[b]);
        if (pos < CAP8)
            buckets[((size_t)(xcd * NPART + b)) * CAP8 + pos] = lbuf[i];
    }
}

// ---------------- Pass B: 8 contiguous segment reads + node sort + final ---
// Partition p reads its 8 XCD-replica segments (each ~1023 entries,
// fully coalesced; no offset-table matrix). Entries+ranks in REGISTERS
// (fully unrolled [8][2] -> static indexing), 1 returning LDS atomic/edge,
// scatter to node-sorted S2, 4-thread/node quad-shuffle reduce, fused
// mask * DSIGMA_DT / cnt epilogue writing out directly.
__global__ __launch_bounds__(BT, 4) void part_kernel(
        const int* __restrict__ gcur,
        const int* __restrict__ buckets,
        const float4* __restrict__ posT,
        const float* __restrict__ x,
        float* __restrict__ out) {
    __shared__ int S2[CAP];                // 36.9 KB node-sorted src ids
    __shared__ int hist[S], base[S];       // 2 KB
    __shared__ float4 ploc[S];             // 4 KB partition's posT slice
    const int p = blockIdx.x, tid = threadIdx.x;
    const int lo = p << S_LOG2;

    if (tid < S) {
        hist[tid] = 0;
        int node = lo + tid;
        ploc[tid] = (node < N_NODES) ? posT[node] : make_float4(0.f, 0.f, 0.f, 0.f);
    }
    __syncthreads();

    // phase 1: 8 coalesced segment reads + rank capture, state in registers
    int len[NXCD];
    int ent[NXCD][2];
    unsigned short prk[NXCD][2];
#pragma unroll
    for (int xx = 0; xx < NXCD; ++xx) {
        len[xx] = min(gcur[(xx * NPART + p) * GSTRIDE], CAP8);
        const int* __restrict__ bp = buckets + ((size_t)(xx * NPART + p)) * CAP8;
#pragma unroll
        for (int r = 0; r < 2; ++r) {
            int i = tid + r * BT;
            if (i < len[xx]) {
                int e = bp[i];
                ent[xx][r] = e;
                prk[xx][r] = (unsigned short)atomicAdd(&hist[e & (S - 1)], 1);
            }
        }
    }
    __syncthreads();

    // exclusive prefix scan of hist[0..256) by wave 0 (4 x 64 with carry)
    if (tid < 64) {
        int carry = 0;
        for (int b = 0; b < S; b += 64) {
            int v = hist[b + tid];
            int orig = v;
#pragma unroll
            for (int d = 1; d < 64; d <<= 1) {
                int t = __shfl_up(v, d, 64);
                if (tid >= d) v += t;
            }
            base[b + tid] = carry + v - orig;
            carry += __shfl(v, 63, 64);
        }
    }
    __syncthreads();

    // phase 2: replay from registers, scatter into node-sorted S2
#pragma unroll
    for (int xx = 0; xx < NXCD; ++xx) {
#pragma unroll
        for (int r = 0; r < 2; ++r) {
            int i = tid + r * BT;
            if (i < len[xx]) {
                int e = ent[xx][r];
                int pos = base[e & (S - 1)] + (int)prk[xx][r];
                if (pos < CAP) S2[pos] = e >> S_LOG2;
            }
        }
    }
    __syncthreads();

    // fused reduce + finalize: 4 threads per node, quad shuffle combine.
    // tid = r*4 + q ; rows r in [0,256), q in [0,4). 1024 = S*4 exactly.
    const int rr = tid >> 2, q = tid & 3;
    const int node = lo + rr;
    const int nseg = hist[rr];
    const int b0 = base[rr];
    const int jend = min(b0 + nseg, CAP);
    float4 b = ploc[rr];
    float ax = 0.f, ay = 0.f, az = 0.f;
    for (int jj = b0 + q; jj < jend; jj += 4) {
        float4 a = posT[S2[jj]];
        float px = a.x - b.x, py = a.y - b.y, pz = a.z - b.z;
        float dT = a.w - b.w;
        float w  = dT / (px * px + py * py + pz * pz + EPS);
        ax += w * px; ay += w * py; az += w * pz;
    }
    ax += __shfl_down(ax, 2, 64); ax += __shfl_down(ax, 1, 64);
    ay += __shfl_down(ay, 2, 64); ay += __shfl_down(ay, 1, 64);
    az += __shfl_down(az, 2, 64); az += __shfl_down(az, 1, 64);
    if (q == 0 && node < N_NODES) {
        float phi = x[node * 9 + 8];
        float cn = nseg > 1 ? (float)nseg : 1.0f;
        float m = (fabsf(phi) < PHI_THRESH) ? (DSIGMA_DT / cn) : 0.0f;
        out[3 * node]     = m * ax;
        out[3 * node + 1] = m * ay;
        out[3 * node + 2] = m * az;
    }
}

// ---------------- fallback: global atomics (small ws) ---------------------
__global__ void prep_kernel(const float* __restrict__ x,
                            const float* __restrict__ pos,
                            float4* __restrict__ posT) {
    int i = blockIdx.x * blockDim.x + threadIdx.x;
    if (i < N_NODES)
        posT[i] = make_float4(pos[3 * i], pos[3 * i + 1], pos[3 * i + 2],
                              x[9 * i + 3]);
}

__global__ void edge_scatter_atomic_kernel(const int* __restrict__ ei,
                                           const float4* __restrict__ posT,
                                           float4* __restrict__ accum) {
    int e = blockIdx.x * blockDim.x + threadIdx.x;
    if (e >= N_EDGES) return;
    int s = ei[e];
    int d = ei[N_EDGES + e];
    float4 a = posT[s];
    float4 b = posT[d];
    float px = a.x - b.x, py = a.y - b.y, pz = a.z - b.z;
    float dT = a.w - b.w;
    float w  = dT / (px * px + py * py + pz * pz + EPS);
    float* ac = (float*)&accum[d];
    atomicAdd(ac,     w * px);
    atomicAdd(ac + 1, w * py);
    atomicAdd(ac + 2, w * pz);
    atomicAdd(ac + 3, 1.0f);
}

__global__ void finalize_accum_kernel(const float* __restrict__ x,
                                      const float4* __restrict__ accum,
                                      float* __restrict__ out) {
    int i = blockIdx.x * blockDim.x + threadIdx.x;
    if (i >= N_NODES) return;
    float4 a = accum[i];
    float phi = x[i * 9 + 8];
    float cn = a.w > 1.0f ? a.w : 1.0f;
    float m = (fabsf(phi) < PHI_THRESH) ? (DSIGMA_DT / cn) : 0.0f;
    out[3 * i]     = m * a.x;
    out[3 * i + 1] = m * a.y;
    out[3 * i + 2] = m * a.z;
}

extern "C" void kernel_launch(void* const* d_in, const int* in_sizes, int n_in,
                              void* d_out, int out_size, void* d_ws, size_t ws_size,
                              hipStream_t stream) {
    const float* x   = (const float*)d_in[0];
    const float* pos = (const float*)d_in[1];
    const int*   ei  = (const int*)d_in[2];
    float* out = (float*)d_out;

    // ws layout: [posT 1.6MB][gcur 200KB padded][buckets 19.2MB] ~ 21MB
    const size_t posT_b = (size_t)N_NODES * sizeof(float4);             // 1.6 MB
    const size_t gcur_b = (size_t)NXCD * NPART * GSTRIDE * sizeof(int); // 200 KB
    const size_t buck_b = (size_t)NXCD * NPART * CAP8 * sizeof(int);    // 19.2 MB

    char* w = (char*)d_ws;
    float4* posT    = (float4*)w;
    int*    gcur    = (int*)(w + posT_b);
    int*    buckets = (int*)(w + posT_b + ((gcur_b + 255) & ~255ull));

    const size_t need_full = posT_b + ((gcur_b + 255) & ~255ull) + buck_b;

    const int B = 256;

    if (ws_size >= need_full) {
        hipMemsetAsync(gcur, 0, gcur_b, stream);
        bin_kernel<<<NB, BT, 0, stream>>>((const int4*)ei, x, pos, posT, gcur, buckets);
        part_kernel<<<NPART, BT, 0, stream>>>(gcur, buckets, posT, x, out);
    } else {
        float4* accum = (float4*)(w + posT_b);  // 1.6 MB
        prep_kernel<<<(N_NODES + B - 1) / B, B, 0, stream>>>(x, pos, posT);
        hipMemsetAsync(accum, 0, (size_t)N_NODES * sizeof(float4), stream);
        edge_scatter_atomic_kernel<<<(N_EDGES + B - 1) / B, B, 0, stream>>>(ei, posT, accum);
        finalize_accum_kernel<<<(N_NODES + B - 1) / B, B, 0, stream>>>(x, accum, out);
    }
}